// Round 17
// baseline (167.286 us; speedup 1.0000x reference)
//
#include <hip/hip_runtime.h>

typedef unsigned short u16;
typedef unsigned int   u32;
typedef __attribute__((ext_vector_type(4))) float f32x4;
typedef __attribute__((ext_vector_type(8))) short s16x8;
typedef __attribute__((ext_vector_type(4))) u32   u32x4;
typedef __attribute__((ext_vector_type(4))) u16   u16x4;

#define DEV static __device__ __forceinline__

DEV float bf2f(u16 a) { union { u32 u; float f; } x; x.u = ((u32)a) << 16; return x.f; }
DEV u16 f2bf(float f) {
  union { float f; u32 u; } x; x.f = f;
  u32 r = (x.u + 0x7FFFu + ((x.u >> 16) & 1u)) >> 16;
  return (u16)r;
}
DEV float wsum(float v) {
#pragma unroll
  for (int m = 32; m; m >>= 1) v += __shfl_xor(v, m, 64);
  return v;
}

// XCD chunked swizzle, bijective for any nwg (m204): each XCD gets a contiguous chunk.
DEV int xcd_swz(int bid, int nwg) {
  int q = nwg >> 3, r = nwg & 7;
  int xcd = bid & 7, idx = bid >> 3;
  return (xcd < r ? xcd * (q + 1) : r * (q + 1) + (xcd - r) * q) + idx;
}

// async 16B global->LDS (wave-uniform LDS base + lane*16; per-lane global src)
DEV void gload16(const void* g, void* l) {
  __builtin_amdgcn_global_load_lds(
      (const __attribute__((address_space(1))) u32*)g,
      (__attribute__((address_space(3))) u32*)l, 16, 0, 0);
}

// swizzled fragment address for rows of 384 B: 16B-slot low-3 bits XOR row&7
DEV const s16x8* frag(const u16* lds, int row, int s) {
  int sw = (s & ~7) | ((s & 7) ^ (row & 7));
  return reinterpret_cast<const s16x8*>(
      reinterpret_cast<const char*>(lds) + row * 384 + sw * 16);
}

// ---------------- constants ----------------
// DIM=192, RES=(8,56,56), HEADS=6, hd=32, WS=(2,7,7), SS=(1,3,3)
// B=2, L=25088, Bn=512 windows, N=98, M=50176 token rows

// ---------------- merged prep: qkv wconv+permute, w1 conv, bias table, LN1 ----------
__global__ __launch_bounds__(256) void k_prep(
    const float* __restrict__ qkvw, const float* __restrict__ qkvb,
    u16* __restrict__ qkvwb, float* __restrict__ pbias,
    const float* __restrict__ w1, u16* __restrict__ w1b,
    const float* __restrict__ relt, u16* __restrict__ biasT,
    const float* __restrict__ x, const float* __restrict__ n1g,
    const float* __restrict__ n1b, u16* __restrict__ xw)
{
  int b = blockIdx.x, tid = threadIdx.x;
  if (b < 108) {
    // qkv weight: permute rows o = head*96+d*3+t -> n' = t*192+head*32+d; scale q rows.
    const float sc = 0.17677669529663687f;  // 32^-0.5
    int i = b * 256 + tid;
    if (i < 27648) {
      int np = i / 48, c = i - np * 48;
      int t = np / 192, rem = np - t * 192;
      int head = rem >> 5, dd = rem & 31;
      int o = head * 96 + dd * 3 + t;
      float s2 = (t == 0) ? sc : 1.f;
      f32x4 v = reinterpret_cast<const f32x4*>(qkvw)[o * 48 + c];
      u16x4 ov; ov[0] = f2bf(v[0] * s2); ov[1] = f2bf(v[1] * s2);
      ov[2] = f2bf(v[2] * s2); ov[3] = f2bf(v[3] * s2);
      reinterpret_cast<u16x4*>(qkvwb)[i] = ov;
    }
    if (i < 576) {
      int t = i / 192, rem = i - t * 192;
      int head = rem >> 5, dd = rem & 31;
      pbias[i] = qkvb[head * 96 + dd * 3 + t] * ((t == 0) ? sc : 1.f);
    }
  } else if (b < 252) {
    int i = (b - 108) * 256 + tid;
    if (i < 36864) {
      f32x4 v = reinterpret_cast<const f32x4*>(w1)[i];
      u16x4 o; o[0] = f2bf(v[0]); o[1] = f2bf(v[1]); o[2] = f2bf(v[2]); o[3] = f2bf(v[3]);
      reinterpret_cast<u16x4*>(w1b)[i] = o;
    }
  } else if (b < 2604) {
    // biasT[class(8)][head(6)][col j(pad 112)][row t(pad 112)] bf16; col pad = -1e30.
    int i = (b - 252) * 256 + tid;   // 8*6*112*112 = 602112
    if (i >= 602112) return;
    int t = i % 112; int rem = i / 112;
    int j = rem % 112; rem /= 112;
    int h = rem % 6; int c = rem / 6;
    if (j >= 98) { biasT[i] = f2bf(-1e30f); return; }
    if (t >= 98) { biasT[i] = 0; return; }
    int td = t >= 49, tr = t - td * 49, th = tr / 7, tw = tr - th * 7;
    int jd = j >= 49, jr = j - jd * 49, jh = jr / 7, jw = jr - jh * 7;
    int lin_t = td * 169 + th * 13 + tw;
    int lin_j = jd * 169 + jh * 13 + jw;
    float bias = relt[(lin_t - lin_j + 253) * 6 + h];
    int cd = (c >> 2) & 1, ch = (c >> 1) & 1, cw = c & 1;
    int cnt_t = (cd ? (1 + td) : 0) * 9 + (ch ? (1 + (th >= 4)) : 0) * 3 + (cw ? (1 + (tw >= 4)) : 0);
    int cnt_j = (cd ? (1 + jd) : 0) * 9 + (ch ? (1 + (jh >= 4)) : 0) * 3 + (cw ? (1 + (jw >= 4)) : 0);
    if (cnt_t != cnt_j) bias -= 100.f;
    biasT[i] = f2bf(bias);
  } else {
    // LN1 + shift + window partition (4 rows / block)
    int row  = (b - 2604) * 4 + (tid >> 6);
    int lane = tid & 63;
    int win = row / 98, tok = row - win * 98;
    int bb = win >> 8, wrem = win & 255;
    int wd = wrem >> 6, wh = (wrem >> 3) & 7, ww = wrem & 7;
    int td = tok >= 49; int tr = tok - td * 49; int th = tr / 7, tw = tr - th * 7;
    int dsrc = (wd * 2 + td + 1) & 7;
    int hs = wh * 7 + th + 3; if (hs >= 56) hs -= 56;
    int wsc = ww * 7 + tw + 3; if (wsc >= 56) wsc -= 56;
    const float* xr = x + ((size_t)bb * 25088 + (size_t)dsrc * 3136 + hs * 56 + wsc) * 192;
    float v0 = xr[lane], v1 = xr[lane + 64], v2 = xr[lane + 128];
    float mu  = wsum(v0 + v1 + v2) * (1.f / 192.f);
    float sq  = wsum(v0 * v0 + v1 * v1 + v2 * v2) * (1.f / 192.f);
    float inv = rsqrtf(sq - mu * mu + 1e-5f);
    u16* orow = xw + (size_t)row * 192;
    orow[lane      ] = f2bf((v0 - mu) * inv * n1g[lane      ] + n1b[lane      ]);
    orow[lane + 64 ] = f2bf((v1 - mu) * inv * n1g[lane + 64 ] + n1b[lane + 64 ]);
    orow[lane + 128] = f2bf((v2 - mu) * inv * n1g[lane + 128] + n1b[lane + 128]);
  }
}

// ---------------- kernel 4: window reverse + residual + LN2 (x2 stored bf16) ---------
__global__ __launch_bounds__(256) void k_merge_ln2(
    const float* __restrict__ x, const u16* __restrict__ ao,
    const float* __restrict__ g, const float* __restrict__ b,
    u16* __restrict__ x2b, u16* __restrict__ xn2)
{
  int m = blockIdx.x * 4 + (threadIdx.x >> 6);
  int lane = threadIdx.x & 63;
  int bb = m / 25088, l = m - bb * 25088;
  int d = l / 3136; int rem = l - d * 3136; int h = rem / 56, w = rem - h * 56;
  int dsh = (d + 7) & 7;
  int hsh = h - 3; if (hsh < 0) hsh += 56;
  int wsh = w - 3; if (wsh < 0) wsh += 56;
  int wd = dsh >> 1, td = dsh & 1;
  int wh = hsh / 7, th = hsh - wh * 7;
  int ww = wsh / 7, tw = wsh - ww * 7;
  int win = (bb << 8) + (wd << 6) + (wh << 3) + ww;
  int tok = td * 49 + th * 7 + tw;
  const u16* ar = ao + ((size_t)win * 98 + tok) * 192;
  const float* xr = x + (size_t)m * 192;
  float v0 = xr[lane      ] + bf2f(ar[lane      ]);
  float v1 = xr[lane + 64 ] + bf2f(ar[lane + 64 ]);
  float v2 = xr[lane + 128] + bf2f(ar[lane + 128]);
  u16* x2r = x2b + (size_t)m * 192;
  x2r[lane] = f2bf(v0); x2r[lane + 64] = f2bf(v1); x2r[lane + 128] = f2bf(v2);
  float mu  = wsum(v0 + v1 + v2) * (1.f / 192.f);
  float sq  = wsum(v0 * v0 + v1 * v1 + v2 * v2) * (1.f / 192.f);
  float inv = rsqrtf(sq - mu * mu + 1e-5f);
  u16* nr = xn2 + (size_t)m * 192;
  nr[lane      ] = f2bf((v0 - mu) * inv * g[lane      ] + b[lane      ]);
  nr[lane + 64 ] = f2bf((v1 - mu) * inv * g[lane + 64 ] + b[lane + 64 ]);
  nr[lane + 128] = f2bf((v2 - mu) * inv * g[lane + 128] + b[lane + 128]);
}

// ---------------- streaming GEMM (K=192): W-slice in REGISTERS, A via gload_lds dbuf --
// MG=8 (round-15 best). mg-MAJOR grid + XCD chunking: A-sharers contiguous -> same XCD.
// RELU instantiation carries 144 tail blocks that convert w2 fp32->bf16 (overlapped).
template<bool RELU, int NTOT>
__global__ __launch_bounds__(256) void k_gemm3(
    const u16* __restrict__ A, const u16* __restrict__ Wb, const float* __restrict__ bias,
    u16* __restrict__ C, const float* __restrict__ w2src, u16* __restrict__ w2dst)
{
  constexpr int MG = 8;
  constexpr int NB = NTOT / 96;
  constexpr int MAINW = NB * 98;
  __shared__ u16 As[2][64 * 192];   // 2 x 24576 B
  int bid = blockIdx.x;
  if (RELU && bid >= MAINW) {
    int i = (bid - MAINW) * 256 + threadIdx.x;
    if (i < 36864) {
      f32x4 v = reinterpret_cast<const f32x4*>(w2src)[i];
      u16x4 o; o[0] = f2bf(v[0]); o[1] = f2bf(v[1]); o[2] = f2bf(v[2]); o[3] = f2bf(v[3]);
      reinterpret_cast<u16x4*>(w2dst)[i] = o;
    }
    return;
  }
  bid = xcd_swz(bid, MAINW);
  int mg = bid / NB, nb = bid - mg * NB;   // mg-major: A-sharers adjacent
  int n0 = nb * 96;
  int m_base = mg * (MG * 64);
  int tid = threadIdx.x, lane = tid & 63, wv = tid >> 6;
  int lr = lane & 15, lg = lane >> 4;
  int wm = wv >> 1, wn = wv & 1;

  auto stage = [&](int buf, int mt) {
    const char* gb = (const char*)(A + (size_t)(m_base + mt * 64) * 192);
    char* lb = (char*)As[buf] + wv * 6144;
#pragma unroll
    for (int c = 0; c < 6144; c += 1024) {
      int o = wv * 6144 + c + lane * 16;
      int row = (int)((u32)o / 384u);
      int slot = (o - row * 384) >> 4;
      int sw = (slot & ~7) | ((slot & 7) ^ (row & 7));
      gload16(gb + (size_t)row * 384 + sw * 16, lb + c);
    }
  };

  stage(0, 0);   // issue first A-tile ASAP; W-loads below overlap its latency

  s16x8 wf[3][6];
  const u16* wbase = Wb + (size_t)(n0 + wn * 48 + lr) * 192 + lg * 8;
#pragma unroll
  for (int nf = 0; nf < 3; ++nf)
#pragma unroll
    for (int ks = 0; ks < 6; ++ks)
      wf[nf][ks] = *reinterpret_cast<const s16x8*>(wbase + (size_t)nf * 16 * 192 + ks * 32);
  float bs[3];
#pragma unroll
  for (int nf = 0; nf < 3; ++nf) bs[nf] = bias[n0 + wn * 48 + nf * 16 + lr];

  __syncthreads();
  for (int i = 0; i < MG; ++i) {
    int cur = i & 1;
    if (i + 1 < MG) stage(cur ^ 1, i + 1);
    f32x4 acc[2][3];
#pragma unroll
    for (int a = 0; a < 2; ++a)
#pragma unroll
      for (int nf = 0; nf < 3; ++nf) acc[a][nf] = {0.f, 0.f, 0.f, 0.f};
#pragma unroll
    for (int ks = 0; ks < 6; ++ks) {
      int s = ks * 4 + lg;
      s16x8 a0 = *frag(As[cur], wm * 32 + lr, s);
      s16x8 a1 = *frag(As[cur], wm * 32 + 16 + lr, s);
#pragma unroll
      for (int nf = 0; nf < 3; ++nf) {
        acc[0][nf] = __builtin_amdgcn_mfma_f32_16x16x32_bf16(a0, wf[nf][ks], acc[0][nf], 0, 0, 0);
        acc[1][nf] = __builtin_amdgcn_mfma_f32_16x16x32_bf16(a1, wf[nf][ks], acc[1][nf], 0, 0, 0);
      }
    }
    int m0 = m_base + i * 64;
#pragma unroll
    for (int mi = 0; mi < 2; ++mi)
#pragma unroll
      for (int nf = 0; nf < 3; ++nf)
#pragma unroll
        for (int r = 0; r < 4; ++r) {
          int m = m0 + wm * 32 + mi * 16 + lg * 4 + r;
          int n = n0 + wn * 48 + nf * 16 + lr;
          float val = acc[mi][nf][r] + bs[nf];
          if (RELU) val = fmaxf(val, 0.f);
          C[(size_t)m * NTOT + n] = f2bf(val);
        }
    __syncthreads();
  }
}

// ---------------- MLP2 GEMM (K=768): k_gemm3-style — A dbuf in LDS, W2 chunk-slice in
// regs (hoisted BEFORE the MFMA cluster), full N per block (4 waves x 48 cols),
// acc[4][3] accumulated over K. 784 blocks, h1 read exactly once. --------------------
__global__ __launch_bounds__(256) void k_mlp2(
    const u16* __restrict__ A, const u16* __restrict__ Wb, const float* __restrict__ bias,
    const u16* __restrict__ x2b, float* __restrict__ of)
{
  __shared__ u16 As[2][64 * 192];   // 2 x 24576 B
  int bid = xcd_swz(blockIdx.x, 784);
  int m0 = bid * 64;
  int tid = threadIdx.x, lane = tid & 63, wv = tid >> 6;
  int lr = lane & 15, lg = lane >> 4;
  int n0 = wv * 48;                 // wave owns 48 of the 192 output cols

  auto stage = [&](int buf, int kc) {
    const char* gb = (const char*)(A + (size_t)m0 * 768 + kc * 192);
    char* lb = (char*)As[buf] + wv * 6144;
#pragma unroll
    for (int c = 0; c < 6144; c += 1024) {
      int o = wv * 6144 + c + lane * 16;
      int row = (int)((u32)o / 384u);
      int slot = (o - row * 384) >> 4;
      int sw = (slot & ~7) | ((slot & 7) ^ (row & 7));
      gload16(gb + (size_t)row * 1536 + sw * 16, lb + c);
    }
  };

  f32x4 acc[4][3];
#pragma unroll
  for (int mi = 0; mi < 4; ++mi)
#pragma unroll
    for (int nf = 0; nf < 3; ++nf) acc[mi][nf] = {0.f, 0.f, 0.f, 0.f};
  float bs[3];
#pragma unroll
  for (int nf = 0; nf < 3; ++nf) bs[nf] = bias[n0 + nf * 16 + lr];

  stage(0, 0);
  __syncthreads();
  for (int kc = 0; kc < 4; ++kc) {
    int cur = kc & 1;
    if (kc < 3) stage(cur ^ 1, kc + 1);
    // hoist this chunk's W fragments into regs (L2-resident, shared across blocks)
    s16x8 wf[3][6];
    const u16* wbase = Wb + (size_t)(n0 + lr) * 768 + kc * 192 + lg * 8;
#pragma unroll
    for (int nf = 0; nf < 3; ++nf)
#pragma unroll
      for (int ks = 0; ks < 6; ++ks)
        wf[nf][ks] = *reinterpret_cast<const s16x8*>(wbase + (size_t)nf * 16 * 768 + ks * 32);
#pragma unroll
    for (int ks = 0; ks < 6; ++ks) {
      int s = ks * 4 + lg;
#pragma unroll
      for (int mi = 0; mi < 4; ++mi) {
        s16x8 a0 = *frag(As[cur], mi * 16 + lr, s);
#pragma unroll
        for (int nf = 0; nf < 3; ++nf)
          acc[mi][nf] = __builtin_amdgcn_mfma_f32_16x16x32_bf16(a0, wf[nf][ks], acc[mi][nf], 0, 0, 0);
      }
    }
    __syncthreads();
  }
#pragma unroll
  for (int mi = 0; mi < 4; ++mi)
#pragma unroll
    for (int nf = 0; nf < 3; ++nf)
#pragma unroll
      for (int r = 0; r < 4; ++r) {
        int m = m0 + mi * 16 + lg * 4 + r;
        int n = n0 + nf * 16 + lr;
        size_t idx = (size_t)m * 192 + n;
        of[idx] = fmaxf(acc[mi][nf][r] + bs[nf], 0.f) + bf2f(x2b[idx]);
      }
}

// ---------------- kernel 3: windowed attention via MFMA -------------------
// 7 waves (448 thr), one 16-row stripe per wave. K fragments staged in LDS once per
// block; bias (incl. mask + col-pad -1e30) folded into MFMA C-operand; no max pass.
__global__ __launch_bounds__(448, 2) void k_attn_mfma(
    const u16* __restrict__ qkvc, const u16* __restrict__ biasT, u16* __restrict__ ao)
{
  __shared__ u16 P[7][16 * 128];   // 28672 B per-wave unnormalized probs, slot-swizzled
  __shared__ u16 Vt[32 * 136];     // 8704 B V transposed (d-major), cols 98..135 zero
  __shared__ u16 Ks[98 * 40];      // 7840 B K rows (pad 40 u16 = 80 B: 16B-aligned)

  int bid = xcd_swz(blockIdx.x, 3072);   // 6 heads of a window land on one XCD (L2 reuse)
  int win = bid / 6, head = bid - win * 6;
  int tid = threadIdx.x, lane = tid & 63, wv = tid >> 6;   // wv = stripe 0..6
  int lr = lane & 15, lg = lane >> 4;
  size_t rb = (size_t)(win * 98) * 576;
  const u16* qp0 = qkvc + rb + head * 32;          // q (pre-scaled)
  const u16* kp0 = qkvc + rb + 192 + head * 32;    // k
  const u16* vp0 = qkvc + rb + 384 + head * 32;    // v

  int wrem = win & 255;
  int wd = wrem >> 6, wh = (wrem >> 3) & 7, ww = wrem & 7;
  int cls = ((wd == 3) ? 4 : 0) | ((wh == 7) ? 2 : 0) | ((ww == 7) ? 1 : 0);
  const u16* bT = biasT + (size_t)(cls * 6 + head) * 112 * 112;

  // ---- wave-local global loads first (8 loads -> stay in flight) ----
  int qrow = wv * 16 + lr; if (qrow > 97) qrow = 97;
  s16x8 qf = *reinterpret_cast<const s16x8*>(qp0 + (size_t)qrow * 576 + lg * 8);
  u16x4 b4[7];
#pragma unroll
  for (int j = 0; j < 7; ++j) {
    int col = j * 16 + lr;                       // 0..111, table covers pad cols
    b4[j] = *reinterpret_cast<const u16x4*>(bT + (size_t)col * 112 + wv * 16 + lg * 4);
  }

  // ---- stage V transposed + K row-major (one pass); zero Vt pad cols ----
  for (int u = tid; u < 98 * 16; u += 448) {
    int tok = u >> 4, dp = (u & 15) * 2;
    u32 w = *reinterpret_cast<const u32*>(vp0 + (size_t)tok * 576 + dp);
    Vt[dp * 136 + tok]       = (u16)(w & 0xFFFFu);
    Vt[(dp + 1) * 136 + tok] = (u16)(w >> 16);
    u32 wk = *reinterpret_cast<const u32*>(kp0 + (size_t)tok * 576 + dp);
    *reinterpret_cast<u32*>(&Ks[tok * 40 + dp]) = wk;
  }
  for (int u = tid; u < 32 * 19; u += 448) {
    int d = u / 19, kslot = u - d * 19;
    *reinterpret_cast<u32*>(reinterpret_cast<char*>(Vt) + d * 272 + 196 + kslot * 4) = 0;
  }
  __syncthreads();

  // ---- QK^T: K fragment from LDS, bias (incl. mask & pad) as the C operand ----
  f32x4 s[7];
  __builtin_amdgcn_s_setprio(1);
#pragma unroll
  for (int j = 0; j < 7; ++j) {
    int row = j * 16 + lr; if (row > 97) row = 97;
    s16x8 kfj = *reinterpret_cast<const s16x8*>(&Ks[row * 40 + lg * 8]);
    f32x4 c4;
#pragma unroll
    for (int r = 0; r < 4; ++r) c4[r] = bf2f(b4[j][r]);
    s[j] = __builtin_amdgcn_mfma_f32_16x16x32_bf16(qf, kfj, c4, 0, 0, 0);
  }
  __builtin_amdgcn_s_setprio(0);

  // ---- softmax without max pass (scores in [-101, ~2]; exp exact in fp32) ----
  float sm[4] = {0.f, 0.f, 0.f, 0.f};
#pragma unroll
  for (int j = 0; j < 7; ++j)
#pragma unroll
    for (int r = 0; r < 4; ++r) {
      float p = __expf(s[j][r]);
      s[j][r] = p;
      sm[r] += p;
    }
#pragma unroll
  for (int m = 1; m < 16; m <<= 1)
#pragma unroll
    for (int r = 0; r < 4; ++r) sm[r] += __shfl_xor(sm[r], m, 64);
  float rinv[4];
#pragma unroll
  for (int r = 0; r < 4; ++r) rinv[r] = 1.f / sm[r];

  // ---- write unnormalized P to this wave's LDS stripe (16B-slot XOR row&7) ----
#pragma unroll
  for (int j = 0; j < 7; ++j) {
    int col = j * 16 + lr;
    int slot = col >> 3, wi = col & 7;
#pragma unroll
    for (int r = 0; r < 4; ++r) {
      int lrow = lg * 4 + r;
      P[wv][lrow * 128 + (((slot ^ (lrow & 7)) << 3) | wi)] = f2bf(s[j][r]);
    }
  }
  if (lane < 32) {
    int lrow = lr;
    int slot = 14 + lg;
    u32x4 z4 = {0u, 0u, 0u, 0u};
    *reinterpret_cast<u32x4*>(&P[wv][lrow * 128 + ((slot ^ (lrow & 7)) << 3)]) = z4;
  }

  // ---- PV (wave-local; no barrier needed) ----
  f32x4 o0 = {0.f, 0.f, 0.f, 0.f}, o1 = {0.f, 0.f, 0.f, 0.f};
  __builtin_amdgcn_s_setprio(1);
#pragma unroll
  for (int kc = 0; kc < 4; ++kc) {
    int slot = kc * 4 + lg;
    s16x8 pf = *reinterpret_cast<const s16x8*>(&P[wv][lr * 128 + ((slot ^ (lr & 7)) << 3)]);
    s16x8 vf0 = *reinterpret_cast<const s16x8*>(&Vt[lr * 136 + kc * 32 + lg * 8]);
    s16x8 vf1 = *reinterpret_cast<const s16x8*>(&Vt[(16 + lr) * 136 + kc * 32 + lg * 8]);
    o0 = __builtin_amdgcn_mfma_f32_16x16x32_bf16(pf, vf0, o0, 0, 0, 0);
    o1 = __builtin_amdgcn_mfma_f32_16x16x32_bf16(pf, vf1, o1, 0, 0, 0);
  }
  __builtin_amdgcn_s_setprio(0);
#pragma unroll
  for (int r = 0; r < 4; ++r) {
    int t = wv * 16 + lg * 4 + r;
    if (t < 98) {
      size_t ob = ((size_t)win * 98 + t) * 192 + head * 32;
      ao[ob + lr]      = f2bf(o0[r] * rinv[r]);
      ao[ob + 16 + lr] = f2bf(o1[r] * rinv[r]);
    }
  }
}

extern "C" void kernel_launch(void* const* d_in, const int* in_sizes, int n_in,
                              void* d_out, int out_size, void* d_ws, size_t ws_size,
                              hipStream_t stream) {
  (void)in_sizes; (void)n_in; (void)out_size; (void)ws_size;
  const float* x    = (const float*)d_in[0];
  const float* n1g  = (const float*)d_in[1];
  const float* n1b  = (const float*)d_in[2];
  const float* qkvw = (const float*)d_in[3];
  const float* qkvb = (const float*)d_in[4];
  const float* relt = (const float*)d_in[5];
  const float* n2g  = (const float*)d_in[6];
  const float* n2b  = (const float*)d_in[7];
  const float* w1   = (const float*)d_in[8];
  const float* b1   = (const float*)d_in[9];
  const float* w2   = (const float*)d_in[10];
  const float* b2   = (const float*)d_in[11];
  float* out = (float*)d_out;
  char* ws = (char*)d_ws;

  constexpr size_t SZB = 50176ull * 192 * 2;  // one bf16 activation plane
  u16*  xw    = (u16*)(ws);               // plane0: xw -> ao -> w2b (sequential lives)
  u16*  qkvc  = (u16*)(ws + SZB);         // 50176 x 576 bf16 (3 planes)
  u16*  x2b   = (u16*)(ws + SZB);         // overlaps qkvc head (dead after attention)
  u16*  xn2   = (u16*)(ws + 3 * SZB);     // overlaps qkvc tail
  u16*  h1    = (u16*)(ws + 4 * SZB);
  u16*  ao    = xw;
  u16*  w2b   = xw;                       // plane0 after merge_ln2 consumed ao

  // d_out head (dead until final GEMM writes it): bf16 weights, permuted bias, biasT.
  u16*   qkvwb = (u16*)out;                            // 221,184 B
  u16*   w1b   = (u16*)((char*)out + 221184);          // 294,912 B
  float* pbias = (float*)((char*)out + 516096);        // 2,304 B
  u16*   biasT = (u16*)((char*)out + 520192);          // 1,204,224 B

  // 1) prep (weights + bias table) fused with LN1 (independent work, overlapped)
  k_prep<<<2604 + 12544, 256, 0, stream>>>(qkvw, qkvb, qkvwb, pbias, w1, w1b, relt, biasT,
                                           x, n1g, n1b, xw);
  // 2) QKV GEMM (MG=8)
  k_gemm3<false, 576><<<6 * 98, 256, 0, stream>>>(xw, qkvwb, pbias, qkvc, nullptr, nullptr);
  // 3) attention
  k_attn_mfma<<<3072, 448, 0, stream>>>(qkvc, biasT, ao);
  // 4) merge + LN2
  k_merge_ln2<<<12544, 256, 0, stream>>>(x, ao, n2g, n2b, x2b, xn2);
  // 5) MLP1 (MG=8; + 144 tail blocks converting w2 -> plane0, overlapped)
  k_gemm3<true, 768><<<8 * 98 + 144, 256, 0, stream>>>(xn2, w1b, b1, h1, w2, w2b);
  // 6) MLP2 + residual (k_gemm3-style, full-N blocks, h1 read once)
  k_mlp2<<<784, 256, 0, stream>>>(h1, w2b, b2, x2b, out);
}

// Round 18
// 149.661 us; speedup vs baseline: 1.1178x; 1.1178x over previous
//
#include <hip/hip_runtime.h>

typedef unsigned short u16;
typedef unsigned int   u32;
typedef __attribute__((ext_vector_type(4))) float f32x4;
typedef __attribute__((ext_vector_type(8))) short s16x8;
typedef __attribute__((ext_vector_type(4))) u32   u32x4;
typedef __attribute__((ext_vector_type(4))) u16   u16x4;

#define DEV static __device__ __forceinline__

DEV float bf2f(u16 a) { union { u32 u; float f; } x; x.u = ((u32)a) << 16; return x.f; }
DEV u16 f2bf(float f) {
  union { float f; u32 u; } x; x.f = f;
  u32 r = (x.u + 0x7FFFu + ((x.u >> 16) & 1u)) >> 16;
  return (u16)r;
}
DEV float wsum(float v) {
#pragma unroll
  for (int m = 32; m; m >>= 1) v += __shfl_xor(v, m, 64);
  return v;
}

// XCD chunked swizzle, bijective for any nwg (m204): each XCD gets a contiguous chunk.
DEV int xcd_swz(int bid, int nwg) {
  int q = nwg >> 3, r = nwg & 7;
  int xcd = bid & 7, idx = bid >> 3;
  return (xcd < r ? xcd * (q + 1) : r * (q + 1) + (xcd - r) * q) + idx;
}

// async 16B global->LDS (wave-uniform LDS base + lane*16; per-lane global src)
DEV void gload16(const void* g, void* l) {
  __builtin_amdgcn_global_load_lds(
      (const __attribute__((address_space(1))) u32*)g,
      (__attribute__((address_space(3))) u32*)l, 16, 0, 0);
}

// swizzled fragment address for rows of 384 B: 16B-slot low-3 bits XOR row&7
DEV const s16x8* frag(const u16* lds, int row, int s) {
  int sw = (s & ~7) | ((s & 7) ^ (row & 7));
  return reinterpret_cast<const s16x8*>(
      reinterpret_cast<const char*>(lds) + row * 384 + sw * 16);
}

// ---------------- constants ----------------
// DIM=192, RES=(8,56,56), HEADS=6, hd=32, WS=(2,7,7), SS=(1,3,3)
// B=2, L=25088, Bn=512 windows, N=98, M=50176 token rows

// ---------------- merged prep: qkv wconv+permute, w1 conv, bias table, LN1 ----------
__global__ __launch_bounds__(256) void k_prep(
    const float* __restrict__ qkvw, const float* __restrict__ qkvb,
    u16* __restrict__ qkvwb, float* __restrict__ pbias,
    const float* __restrict__ w1, u16* __restrict__ w1b,
    const float* __restrict__ relt, u16* __restrict__ biasT,
    const float* __restrict__ x, const float* __restrict__ n1g,
    const float* __restrict__ n1b, u16* __restrict__ xw)
{
  int b = blockIdx.x, tid = threadIdx.x;
  if (b < 108) {
    // qkv weight: permute rows o = head*96+d*3+t -> n' = t*192+head*32+d; scale q rows.
    const float sc = 0.17677669529663687f;  // 32^-0.5
    int i = b * 256 + tid;
    if (i < 27648) {
      int np = i / 48, c = i - np * 48;
      int t = np / 192, rem = np - t * 192;
      int head = rem >> 5, dd = rem & 31;
      int o = head * 96 + dd * 3 + t;
      float s2 = (t == 0) ? sc : 1.f;
      f32x4 v = reinterpret_cast<const f32x4*>(qkvw)[o * 48 + c];
      u16x4 ov; ov[0] = f2bf(v[0] * s2); ov[1] = f2bf(v[1] * s2);
      ov[2] = f2bf(v[2] * s2); ov[3] = f2bf(v[3] * s2);
      reinterpret_cast<u16x4*>(qkvwb)[i] = ov;
    }
    if (i < 576) {
      int t = i / 192, rem = i - t * 192;
      int head = rem >> 5, dd = rem & 31;
      pbias[i] = qkvb[head * 96 + dd * 3 + t] * ((t == 0) ? sc : 1.f);
    }
  } else if (b < 252) {
    int i = (b - 108) * 256 + tid;
    if (i < 36864) {
      f32x4 v = reinterpret_cast<const f32x4*>(w1)[i];
      u16x4 o; o[0] = f2bf(v[0]); o[1] = f2bf(v[1]); o[2] = f2bf(v[2]); o[3] = f2bf(v[3]);
      reinterpret_cast<u16x4*>(w1b)[i] = o;
    }
  } else if (b < 2604) {
    // biasT[class(8)][head(6)][col j(pad 112)][row t(pad 112)] bf16; col pad = -1e30.
    int i = (b - 252) * 256 + tid;   // 8*6*112*112 = 602112
    if (i >= 602112) return;
    int t = i % 112; int rem = i / 112;
    int j = rem % 112; rem /= 112;
    int h = rem % 6; int c = rem / 6;
    if (j >= 98) { biasT[i] = f2bf(-1e30f); return; }
    if (t >= 98) { biasT[i] = 0; return; }
    int td = t >= 49, tr = t - td * 49, th = tr / 7, tw = tr - th * 7;
    int jd = j >= 49, jr = j - jd * 49, jh = jr / 7, jw = jr - jh * 7;
    int lin_t = td * 169 + th * 13 + tw;
    int lin_j = jd * 169 + jh * 13 + jw;
    float bias = relt[(lin_t - lin_j + 253) * 6 + h];
    int cd = (c >> 2) & 1, ch = (c >> 1) & 1, cw = c & 1;
    int cnt_t = (cd ? (1 + td) : 0) * 9 + (ch ? (1 + (th >= 4)) : 0) * 3 + (cw ? (1 + (tw >= 4)) : 0);
    int cnt_j = (cd ? (1 + jd) : 0) * 9 + (ch ? (1 + (jh >= 4)) : 0) * 3 + (cw ? (1 + (jw >= 4)) : 0);
    if (cnt_t != cnt_j) bias -= 100.f;
    biasT[i] = f2bf(bias);
  } else {
    // LN1 + shift + window partition (4 rows / block)
    int row  = (b - 2604) * 4 + (tid >> 6);
    int lane = tid & 63;
    int win = row / 98, tok = row - win * 98;
    int bb = win >> 8, wrem = win & 255;
    int wd = wrem >> 6, wh = (wrem >> 3) & 7, ww = wrem & 7;
    int td = tok >= 49; int tr = tok - td * 49; int th = tr / 7, tw = tr - th * 7;
    int dsrc = (wd * 2 + td + 1) & 7;
    int hs = wh * 7 + th + 3; if (hs >= 56) hs -= 56;
    int wsc = ww * 7 + tw + 3; if (wsc >= 56) wsc -= 56;
    const float* xr = x + ((size_t)bb * 25088 + (size_t)dsrc * 3136 + hs * 56 + wsc) * 192;
    float v0 = xr[lane], v1 = xr[lane + 64], v2 = xr[lane + 128];
    float mu  = wsum(v0 + v1 + v2) * (1.f / 192.f);
    float sq  = wsum(v0 * v0 + v1 * v1 + v2 * v2) * (1.f / 192.f);
    float inv = rsqrtf(sq - mu * mu + 1e-5f);
    u16* orow = xw + (size_t)row * 192;
    orow[lane      ] = f2bf((v0 - mu) * inv * n1g[lane      ] + n1b[lane      ]);
    orow[lane + 64 ] = f2bf((v1 - mu) * inv * n1g[lane + 64 ] + n1b[lane + 64 ]);
    orow[lane + 128] = f2bf((v2 - mu) * inv * n1g[lane + 128] + n1b[lane + 128]);
  }
}

// ---------------- kernel 4: window reverse + residual + LN2 (x2 stored bf16) ---------
__global__ __launch_bounds__(256) void k_merge_ln2(
    const float* __restrict__ x, const u16* __restrict__ ao,
    const float* __restrict__ g, const float* __restrict__ b,
    u16* __restrict__ x2b, u16* __restrict__ xn2)
{
  int m = blockIdx.x * 4 + (threadIdx.x >> 6);
  int lane = threadIdx.x & 63;
  int bb = m / 25088, l = m - bb * 25088;
  int d = l / 3136; int rem = l - d * 3136; int h = rem / 56, w = rem - h * 56;
  int dsh = (d + 7) & 7;
  int hsh = h - 3; if (hsh < 0) hsh += 56;
  int wsh = w - 3; if (wsh < 0) wsh += 56;
  int wd = dsh >> 1, td = dsh & 1;
  int wh = hsh / 7, th = hsh - wh * 7;
  int ww = wsh / 7, tw = wsh - ww * 7;
  int win = (bb << 8) + (wd << 6) + (wh << 3) + ww;
  int tok = td * 49 + th * 7 + tw;
  const u16* ar = ao + ((size_t)win * 98 + tok) * 192;
  const float* xr = x + (size_t)m * 192;
  float v0 = xr[lane      ] + bf2f(ar[lane      ]);
  float v1 = xr[lane + 64 ] + bf2f(ar[lane + 64 ]);
  float v2 = xr[lane + 128] + bf2f(ar[lane + 128]);
  u16* x2r = x2b + (size_t)m * 192;
  x2r[lane] = f2bf(v0); x2r[lane + 64] = f2bf(v1); x2r[lane + 128] = f2bf(v2);
  float mu  = wsum(v0 + v1 + v2) * (1.f / 192.f);
  float sq  = wsum(v0 * v0 + v1 * v1 + v2 * v2) * (1.f / 192.f);
  float inv = rsqrtf(sq - mu * mu + 1e-5f);
  u16* nr = xn2 + (size_t)m * 192;
  nr[lane      ] = f2bf((v0 - mu) * inv * g[lane      ] + b[lane      ]);
  nr[lane + 64 ] = f2bf((v1 - mu) * inv * g[lane + 64 ] + b[lane + 64 ]);
  nr[lane + 128] = f2bf((v2 - mu) * inv * g[lane + 128] + b[lane + 128]);
}

// ---------------- streaming GEMM (K=192): W-slice in REGISTERS, A via gload_lds dbuf --
// mg-MAJOR grid: the NB blocks sharing an A-slice are contiguous -> same XCD chunk ->
// A-slice fetched once per XCD (fixes the 4x A-over-fetch seen at nb-major).
// RELU instantiation carries 144 tail blocks that convert w2 fp32->bf16 (overlapped).
template<bool RELU, int NTOT>
__global__ __launch_bounds__(256) void k_gemm3(
    const u16* __restrict__ A, const u16* __restrict__ Wb, const float* __restrict__ bias,
    u16* __restrict__ C, const float* __restrict__ w2src, u16* __restrict__ w2dst)
{
  constexpr int MG = 8;
  constexpr int NB = NTOT / 96;
  constexpr int MAINW = NB * 98;
  __shared__ u16 As[2][64 * 192];   // 2 x 24576 B
  int bid = blockIdx.x;
  if (RELU && bid >= MAINW) {
    int i = (bid - MAINW) * 256 + threadIdx.x;
    if (i < 36864) {
      f32x4 v = reinterpret_cast<const f32x4*>(w2src)[i];
      u16x4 o; o[0] = f2bf(v[0]); o[1] = f2bf(v[1]); o[2] = f2bf(v[2]); o[3] = f2bf(v[3]);
      reinterpret_cast<u16x4*>(w2dst)[i] = o;
    }
    return;
  }
  bid = xcd_swz(bid, MAINW);
  int mg = bid / NB, nb = bid - mg * NB;   // mg-major: A-sharers adjacent
  int n0 = nb * 96;
  int m_base = mg * (MG * 64);
  int tid = threadIdx.x, lane = tid & 63, wv = tid >> 6;
  int lr = lane & 15, lg = lane >> 4;
  int wm = wv >> 1, wn = wv & 1;

  auto stage = [&](int buf, int mt) {
    const char* gb = (const char*)(A + (size_t)(m_base + mt * 64) * 192);
    char* lb = (char*)As[buf] + wv * 6144;
#pragma unroll
    for (int c = 0; c < 6144; c += 1024) {
      int o = wv * 6144 + c + lane * 16;
      int row = (int)((u32)o / 384u);
      int slot = (o - row * 384) >> 4;
      int sw = (slot & ~7) | ((slot & 7) ^ (row & 7));
      gload16(gb + (size_t)row * 384 + sw * 16, lb + c);
    }
  };

  stage(0, 0);   // issue first A-tile ASAP; W-loads below overlap its latency

  s16x8 wf[3][6];
  const u16* wbase = Wb + (size_t)(n0 + wn * 48 + lr) * 192 + lg * 8;
#pragma unroll
  for (int nf = 0; nf < 3; ++nf)
#pragma unroll
    for (int ks = 0; ks < 6; ++ks)
      wf[nf][ks] = *reinterpret_cast<const s16x8*>(wbase + (size_t)nf * 16 * 192 + ks * 32);
  float bs[3];
#pragma unroll
  for (int nf = 0; nf < 3; ++nf) bs[nf] = bias[n0 + wn * 48 + nf * 16 + lr];

  __syncthreads();
  for (int i = 0; i < MG; ++i) {
    int cur = i & 1;
    if (i + 1 < MG) stage(cur ^ 1, i + 1);
    f32x4 acc[2][3];
#pragma unroll
    for (int a = 0; a < 2; ++a)
#pragma unroll
      for (int nf = 0; nf < 3; ++nf) acc[a][nf] = {0.f, 0.f, 0.f, 0.f};
#pragma unroll
    for (int ks = 0; ks < 6; ++ks) {
      int s = ks * 4 + lg;
      s16x8 a0 = *frag(As[cur], wm * 32 + lr, s);
      s16x8 a1 = *frag(As[cur], wm * 32 + 16 + lr, s);
#pragma unroll
      for (int nf = 0; nf < 3; ++nf) {
        acc[0][nf] = __builtin_amdgcn_mfma_f32_16x16x32_bf16(a0, wf[nf][ks], acc[0][nf], 0, 0, 0);
        acc[1][nf] = __builtin_amdgcn_mfma_f32_16x16x32_bf16(a1, wf[nf][ks], acc[1][nf], 0, 0, 0);
      }
    }
    int m0 = m_base + i * 64;
#pragma unroll
    for (int mi = 0; mi < 2; ++mi)
#pragma unroll
      for (int nf = 0; nf < 3; ++nf)
#pragma unroll
        for (int r = 0; r < 4; ++r) {
          int m = m0 + wm * 32 + mi * 16 + lg * 4 + r;
          int n = n0 + wn * 48 + nf * 16 + lr;
          float val = acc[mi][nf][r] + bs[nf];
          if (RELU) val = fmaxf(val, 0.f);
          C[(size_t)m * NTOT + n] = f2bf(val);
        }
    __syncthreads();
  }
}

// ---------------- MLP2 GEMM (K=768): 512 thr / 8 waves, LDS-staged A+W ----------
// mb-major: the 2 blocks sharing an A-slice are adjacent -> same XCD.
__global__ __launch_bounds__(512) void k_gemm2mlp2(
    const u16* __restrict__ A, const u16* __restrict__ Wb, const float* __restrict__ bias,
    const u16* __restrict__ x2b, float* __restrict__ of)
{
  constexpr int MB = 784;
  constexpr int KTOT = 768;
  __shared__ u16 As[64 * 192];     // 24576 B
  __shared__ u16 Ws[96 * 192];     // 36864 B
  int bid = xcd_swz(blockIdx.x, 2 * MB);
  int mb = bid >> 1, nb = bid & 1;
  int m0 = mb * 64, n0 = nb * 96;
  int tid = threadIdx.x, lane = tid & 63, wv = tid >> 6;
  int lr = lane & 15, lg = lane >> 4;
  int wm = wv >> 1, wn = wv & 1;

  f32x4 acc[3];
#pragma unroll
  for (int j = 0; j < 3; ++j) acc[j] = {0.f, 0.f, 0.f, 0.f};

  for (int kc = 0; kc < 4; ++kc) {
    if (kc) __syncthreads();
    if (wv < 4) {
      const char* gb = (const char*)(A + (size_t)m0 * KTOT + kc * 192);
      int base = wv * 6144;
#pragma unroll
      for (int c = 0; c < 6144; c += 1024) {
        int o = base + c + lane * 16;
        int row = (int)((u32)o / 384u);
        int slot = (o - row * 384) >> 4;
        int sw = (slot & ~7) | ((slot & 7) ^ (row & 7));
        gload16(gb + (size_t)row * (KTOT * 2) + sw * 16, (char*)As + base + c);
      }
    } else {
      const char* gb = (const char*)(Wb + (size_t)n0 * KTOT + kc * 192);
      int base = (wv - 4) * 9216;
#pragma unroll
      for (int c = 0; c < 9216; c += 1024) {
        int o = base + c + lane * 16;
        int row = (int)((u32)o / 384u);
        int slot = (o - row * 384) >> 4;
        int sw = (slot & ~7) | ((slot & 7) ^ (row & 7));
        gload16(gb + (size_t)row * (KTOT * 2) + sw * 16, (char*)Ws + base + c);
      }
    }
    __syncthreads();
#pragma unroll
    for (int ks = 0; ks < 6; ++ks) {
      int s = ks * 4 + lg;
      s16x8 a0 = *frag(As, wm * 16 + lr, s);
#pragma unroll
      for (int nf = 0; nf < 3; ++nf) {
        s16x8 bfr = *frag(Ws, wn * 48 + nf * 16 + lr, s);
        acc[nf] = __builtin_amdgcn_mfma_f32_16x16x32_bf16(a0, bfr, acc[nf], 0, 0, 0);
      }
    }
  }
#pragma unroll
  for (int nf = 0; nf < 3; ++nf)
#pragma unroll
    for (int r = 0; r < 4; ++r) {
      int m = m0 + wm * 16 + lg * 4 + r;
      int n = n0 + wn * 48 + nf * 16 + lr;
      size_t idx = (size_t)m * 192 + n;
      of[idx] = fmaxf(acc[nf][r] + bias[n], 0.f) + bf2f(x2b[idx]);
    }
}

// ---------------- kernel 3: windowed attention via MFMA -------------------
// 7 waves (448 thr), one 16-row stripe per wave. K fragments staged in LDS once per
// block; bias (incl. mask + col-pad -1e30) folded into MFMA C-operand; no max pass.
__global__ __launch_bounds__(448, 2) void k_attn_mfma(
    const u16* __restrict__ qkvc, const u16* __restrict__ biasT, u16* __restrict__ ao)
{
  __shared__ u16 P[7][16 * 128];   // 28672 B per-wave unnormalized probs, slot-swizzled
  __shared__ u16 Vt[32 * 136];     // 8704 B V transposed (d-major), cols 98..135 zero
  __shared__ u16 Ks[98 * 40];      // 7840 B K rows (pad 40 u16 = 80 B: 16B-aligned)

  int bid = xcd_swz(blockIdx.x, 3072);   // 6 heads of a window land on one XCD (L2 reuse)
  int win = bid / 6, head = bid - win * 6;
  int tid = threadIdx.x, lane = tid & 63, wv = tid >> 6;   // wv = stripe 0..6
  int lr = lane & 15, lg = lane >> 4;
  size_t rb = (size_t)(win * 98) * 576;
  const u16* qp0 = qkvc + rb + head * 32;          // q (pre-scaled)
  const u16* kp0 = qkvc + rb + 192 + head * 32;    // k
  const u16* vp0 = qkvc + rb + 384 + head * 32;    // v

  int wrem = win & 255;
  int wd = wrem >> 6, wh = (wrem >> 3) & 7, ww = wrem & 7;
  int cls = ((wd == 3) ? 4 : 0) | ((wh == 7) ? 2 : 0) | ((ww == 7) ? 1 : 0);
  const u16* bT = biasT + (size_t)(cls * 6 + head) * 112 * 112;

  // ---- wave-local global loads first (8 loads -> stay in flight) ----
  int qrow = wv * 16 + lr; if (qrow > 97) qrow = 97;
  s16x8 qf = *reinterpret_cast<const s16x8*>(qp0 + (size_t)qrow * 576 + lg * 8);
  u16x4 b4[7];
#pragma unroll
  for (int j = 0; j < 7; ++j) {
    int col = j * 16 + lr;                       // 0..111, table covers pad cols
    b4[j] = *reinterpret_cast<const u16x4*>(bT + (size_t)col * 112 + wv * 16 + lg * 4);
  }

  // ---- stage V transposed + K row-major (one pass); zero Vt pad cols ----
  for (int u = tid; u < 98 * 16; u += 448) {
    int tok = u >> 4, dp = (u & 15) * 2;
    u32 w = *reinterpret_cast<const u32*>(vp0 + (size_t)tok * 576 + dp);
    Vt[dp * 136 + tok]       = (u16)(w & 0xFFFFu);
    Vt[(dp + 1) * 136 + tok] = (u16)(w >> 16);
    u32 wk = *reinterpret_cast<const u32*>(kp0 + (size_t)tok * 576 + dp);
    *reinterpret_cast<u32*>(&Ks[tok * 40 + dp]) = wk;
  }
  for (int u = tid; u < 32 * 19; u += 448) {
    int d = u / 19, kslot = u - d * 19;
    *reinterpret_cast<u32*>(reinterpret_cast<char*>(Vt) + d * 272 + 196 + kslot * 4) = 0;
  }
  __syncthreads();

  // ---- QK^T: K fragment from LDS, bias (incl. mask & pad) as the C operand ----
  f32x4 s[7];
  __builtin_amdgcn_s_setprio(1);
#pragma unroll
  for (int j = 0; j < 7; ++j) {
    int row = j * 16 + lr; if (row > 97) row = 97;
    s16x8 kfj = *reinterpret_cast<const s16x8*>(&Ks[row * 40 + lg * 8]);
    f32x4 c4;
#pragma unroll
    for (int r = 0; r < 4; ++r) c4[r] = bf2f(b4[j][r]);
    s[j] = __builtin_amdgcn_mfma_f32_16x16x32_bf16(qf, kfj, c4, 0, 0, 0);
  }
  __builtin_amdgcn_s_setprio(0);

  // ---- softmax without max pass (scores in [-101, ~2]; exp exact in fp32) ----
  float sm[4] = {0.f, 0.f, 0.f, 0.f};
#pragma unroll
  for (int j = 0; j < 7; ++j)
#pragma unroll
    for (int r = 0; r < 4; ++r) {
      float p = __expf(s[j][r]);
      s[j][r] = p;
      sm[r] += p;
    }
#pragma unroll
  for (int m = 1; m < 16; m <<= 1)
#pragma unroll
    for (int r = 0; r < 4; ++r) sm[r] += __shfl_xor(sm[r], m, 64);
  float rinv[4];
#pragma unroll
  for (int r = 0; r < 4; ++r) rinv[r] = 1.f / sm[r];

  // ---- write unnormalized P to this wave's LDS stripe (16B-slot XOR row&7) ----
#pragma unroll
  for (int j = 0; j < 7; ++j) {
    int col = j * 16 + lr;
    int slot = col >> 3, wi = col & 7;
#pragma unroll
    for (int r = 0; r < 4; ++r) {
      int lrow = lg * 4 + r;
      P[wv][lrow * 128 + (((slot ^ (lrow & 7)) << 3) | wi)] = f2bf(s[j][r]);
    }
  }
  if (lane < 32) {
    int lrow = lr;
    int slot = 14 + lg;
    u32x4 z4 = {0u, 0u, 0u, 0u};
    *reinterpret_cast<u32x4*>(&P[wv][lrow * 128 + ((slot ^ (lrow & 7)) << 3)]) = z4;
  }

  // ---- PV (wave-local; no barrier needed) ----
  f32x4 o0 = {0.f, 0.f, 0.f, 0.f}, o1 = {0.f, 0.f, 0.f, 0.f};
  __builtin_amdgcn_s_setprio(1);
#pragma unroll
  for (int kc = 0; kc < 4; ++kc) {
    int slot = kc * 4 + lg;
    s16x8 pf = *reinterpret_cast<const s16x8*>(&P[wv][lr * 128 + ((slot ^ (lr & 7)) << 3)]);
    s16x8 vf0 = *reinterpret_cast<const s16x8*>(&Vt[lr * 136 + kc * 32 + lg * 8]);
    s16x8 vf1 = *reinterpret_cast<const s16x8*>(&Vt[(16 + lr) * 136 + kc * 32 + lg * 8]);
    o0 = __builtin_amdgcn_mfma_f32_16x16x32_bf16(pf, vf0, o0, 0, 0, 0);
    o1 = __builtin_amdgcn_mfma_f32_16x16x32_bf16(pf, vf1, o1, 0, 0, 0);
  }
  __builtin_amdgcn_s_setprio(0);
#pragma unroll
  for (int r = 0; r < 4; ++r) {
    int t = wv * 16 + lg * 4 + r;
    if (t < 98) {
      size_t ob = ((size_t)win * 98 + t) * 192 + head * 32;
      ao[ob + lr]      = f2bf(o0[r] * rinv[r]);
      ao[ob + 16 + lr] = f2bf(o1[r] * rinv[r]);
    }
  }
}

extern "C" void kernel_launch(void* const* d_in, const int* in_sizes, int n_in,
                              void* d_out, int out_size, void* d_ws, size_t ws_size,
                              hipStream_t stream) {
  (void)in_sizes; (void)n_in; (void)out_size; (void)ws_size;
  const float* x    = (const float*)d_in[0];
  const float* n1g  = (const float*)d_in[1];
  const float* n1b  = (const float*)d_in[2];
  const float* qkvw = (const float*)d_in[3];
  const float* qkvb = (const float*)d_in[4];
  const float* relt = (const float*)d_in[5];
  const float* n2g  = (const float*)d_in[6];
  const float* n2b  = (const float*)d_in[7];
  const float* w1   = (const float*)d_in[8];
  const float* b1   = (const float*)d_in[9];
  const float* w2   = (const float*)d_in[10];
  const float* b2   = (const float*)d_in[11];
  float* out = (float*)d_out;
  char* ws = (char*)d_ws;

  constexpr size_t SZB = 50176ull * 192 * 2;  // one bf16 activation plane
  u16*  xw    = (u16*)(ws);               // plane0: xw -> ao -> w2b (sequential lives)
  u16*  qkvc  = (u16*)(ws + SZB);         // 50176 x 576 bf16 (3 planes)
  u16*  x2b   = (u16*)(ws + SZB);         // overlaps qkvc head (dead after attention)
  u16*  xn2   = (u16*)(ws + 3 * SZB);     // overlaps qkvc tail
  u16*  h1    = (u16*)(ws + 4 * SZB);
  u16*  ao    = xw;
  u16*  w2b   = xw;                       // plane0 after merge_ln2 consumed ao

  // d_out head (dead until final GEMM writes it): bf16 weights, permuted bias, biasT.
  u16*   qkvwb = (u16*)out;                            // 221,184 B
  u16*   w1b   = (u16*)((char*)out + 221184);          // 294,912 B
  float* pbias = (float*)((char*)out + 516096);        // 2,304 B
  u16*   biasT = (u16*)((char*)out + 520192);          // 1,204,224 B

  // 1) prep (weights + bias table) fused with LN1 (independent work, overlapped)
  k_prep<<<2604 + 12544, 256, 0, stream>>>(qkvw, qkvb, qkvwb, pbias, w1, w1b, relt, biasT,
                                           x, n1g, n1b, xw);
  // 2) QKV GEMM
  k_gemm3<false, 576><<<6 * 98, 256, 0, stream>>>(xw, qkvwb, pbias, qkvc, nullptr, nullptr);
  // 3) attention
  k_attn_mfma<<<3072, 448, 0, stream>>>(qkvc, biasT, ao);
  // 4) merge + LN2
  k_merge_ln2<<<12544, 256, 0, stream>>>(x, ao, n2g, n2b, x2b, xn2);
  // 5) MLP1 (+ 144 tail blocks converting w2 -> plane0, overlapped)
  k_gemm3<true, 768><<<8 * 98 + 144, 256, 0, stream>>>(xn2, w1b, b1, h1, w2, w2b);
  // 6) MLP2 + residual
  k_gemm2mlp2<<<784 * 2, 512, 0, stream>>>(h1, w2b, b2, x2b, out);
}

// Round 19
// 148.154 us; speedup vs baseline: 1.1291x; 1.0102x over previous
//
#include <hip/hip_runtime.h>

typedef unsigned short u16;
typedef unsigned int   u32;
typedef __attribute__((ext_vector_type(4))) float f32x4;
typedef __attribute__((ext_vector_type(8))) short s16x8;
typedef __attribute__((ext_vector_type(4))) u32   u32x4;
typedef __attribute__((ext_vector_type(4))) u16   u16x4;

#define DEV static __device__ __forceinline__

DEV float bf2f(u16 a) { union { u32 u; float f; } x; x.u = ((u32)a) << 16; return x.f; }
DEV u16 f2bf(float f) {
  union { float f; u32 u; } x; x.f = f;
  u32 r = (x.u + 0x7FFFu + ((x.u >> 16) & 1u)) >> 16;
  return (u16)r;
}
DEV float wsum(float v) {
#pragma unroll
  for (int m = 32; m; m >>= 1) v += __shfl_xor(v, m, 64);
  return v;
}

// XCD chunked swizzle, bijective for any nwg (m204): each XCD gets a contiguous chunk.
DEV int xcd_swz(int bid, int nwg) {
  int q = nwg >> 3, r = nwg & 7;
  int xcd = bid & 7, idx = bid >> 3;
  return (xcd < r ? xcd * (q + 1) : r * (q + 1) + (xcd - r) * q) + idx;
}

// async 16B global->LDS (wave-uniform LDS base + lane*16; per-lane global src)
DEV void gload16(const void* g, void* l) {
  __builtin_amdgcn_global_load_lds(
      (const __attribute__((address_space(1))) u32*)g,
      (__attribute__((address_space(3))) u32*)l, 16, 0, 0);
}

// swizzled fragment address for rows of 384 B: 16B-slot low-3 bits XOR row&7
DEV const s16x8* frag(const u16* lds, int row, int s) {
  int sw = (s & ~7) | ((s & 7) ^ (row & 7));
  return reinterpret_cast<const s16x8*>(
      reinterpret_cast<const char*>(lds) + row * 384 + sw * 16);
}

// ---------------- constants ----------------
// DIM=192, RES=(8,56,56), HEADS=6, hd=32, WS=(2,7,7), SS=(1,3,3)
// B=2, L=25088, Bn=512 windows, N=98, M=50176 token rows

// ---------------- merged prep: qkv wconv+permute, w1 conv, bias table, LN1 ----------
__global__ __launch_bounds__(256) void k_prep(
    const float* __restrict__ qkvw, const float* __restrict__ qkvb,
    u16* __restrict__ qkvwb, float* __restrict__ pbias,
    const float* __restrict__ w1, u16* __restrict__ w1b,
    const float* __restrict__ relt, u16* __restrict__ biasT,
    const float* __restrict__ x, const float* __restrict__ n1g,
    const float* __restrict__ n1b, u16* __restrict__ xw)
{
  int b = blockIdx.x, tid = threadIdx.x;
  if (b < 108) {
    // qkv weight: permute rows o = head*96+d*3+t -> n' = t*192+head*32+d; scale q rows.
    const float sc = 0.17677669529663687f;  // 32^-0.5
    int i = b * 256 + tid;
    if (i < 27648) {
      int np = i / 48, c = i - np * 48;
      int t = np / 192, rem = np - t * 192;
      int head = rem >> 5, dd = rem & 31;
      int o = head * 96 + dd * 3 + t;
      float s2 = (t == 0) ? sc : 1.f;
      f32x4 v = reinterpret_cast<const f32x4*>(qkvw)[o * 48 + c];
      u16x4 ov; ov[0] = f2bf(v[0] * s2); ov[1] = f2bf(v[1] * s2);
      ov[2] = f2bf(v[2] * s2); ov[3] = f2bf(v[3] * s2);
      reinterpret_cast<u16x4*>(qkvwb)[i] = ov;
    }
    if (i < 576) {
      int t = i / 192, rem = i - t * 192;
      int head = rem >> 5, dd = rem & 31;
      pbias[i] = qkvb[head * 96 + dd * 3 + t] * ((t == 0) ? sc : 1.f);
    }
  } else if (b < 252) {
    int i = (b - 108) * 256 + tid;
    if (i < 36864) {
      f32x4 v = reinterpret_cast<const f32x4*>(w1)[i];
      u16x4 o; o[0] = f2bf(v[0]); o[1] = f2bf(v[1]); o[2] = f2bf(v[2]); o[3] = f2bf(v[3]);
      reinterpret_cast<u16x4*>(w1b)[i] = o;
    }
  } else if (b < 2604) {
    // biasT[class(8)][head(6)][col j(pad 112)][row t(pad 112)] bf16; col pad = -1e30.
    int i = (b - 252) * 256 + tid;   // 8*6*112*112 = 602112
    if (i >= 602112) return;
    int t = i % 112; int rem = i / 112;
    int j = rem % 112; rem /= 112;
    int h = rem % 6; int c = rem / 6;
    if (j >= 98) { biasT[i] = f2bf(-1e30f); return; }
    if (t >= 98) { biasT[i] = 0; return; }
    int td = t >= 49, tr = t - td * 49, th = tr / 7, tw = tr - th * 7;
    int jd = j >= 49, jr = j - jd * 49, jh = jr / 7, jw = jr - jh * 7;
    int lin_t = td * 169 + th * 13 + tw;
    int lin_j = jd * 169 + jh * 13 + jw;
    float bias = relt[(lin_t - lin_j + 253) * 6 + h];
    int cd = (c >> 2) & 1, ch = (c >> 1) & 1, cw = c & 1;
    int cnt_t = (cd ? (1 + td) : 0) * 9 + (ch ? (1 + (th >= 4)) : 0) * 3 + (cw ? (1 + (tw >= 4)) : 0);
    int cnt_j = (cd ? (1 + jd) : 0) * 9 + (ch ? (1 + (jh >= 4)) : 0) * 3 + (cw ? (1 + (jw >= 4)) : 0);
    if (cnt_t != cnt_j) bias -= 100.f;
    biasT[i] = f2bf(bias);
  } else {
    // LN1 + shift + window partition (4 rows / block)
    int row  = (b - 2604) * 4 + (tid >> 6);
    int lane = tid & 63;
    int win = row / 98, tok = row - win * 98;
    int bb = win >> 8, wrem = win & 255;
    int wd = wrem >> 6, wh = (wrem >> 3) & 7, ww = wrem & 7;
    int td = tok >= 49; int tr = tok - td * 49; int th = tr / 7, tw = tr - th * 7;
    int dsrc = (wd * 2 + td + 1) & 7;
    int hs = wh * 7 + th + 3; if (hs >= 56) hs -= 56;
    int wsc = ww * 7 + tw + 3; if (wsc >= 56) wsc -= 56;
    const float* xr = x + ((size_t)bb * 25088 + (size_t)dsrc * 3136 + hs * 56 + wsc) * 192;
    float v0 = xr[lane], v1 = xr[lane + 64], v2 = xr[lane + 128];
    float mu  = wsum(v0 + v1 + v2) * (1.f / 192.f);
    float sq  = wsum(v0 * v0 + v1 * v1 + v2 * v2) * (1.f / 192.f);
    float inv = rsqrtf(sq - mu * mu + 1e-5f);
    u16* orow = xw + (size_t)row * 192;
    orow[lane      ] = f2bf((v0 - mu) * inv * n1g[lane      ] + n1b[lane      ]);
    orow[lane + 64 ] = f2bf((v1 - mu) * inv * n1g[lane + 64 ] + n1b[lane + 64 ]);
    orow[lane + 128] = f2bf((v2 - mu) * inv * n1g[lane + 128] + n1b[lane + 128]);
  }
}

// ---------------- kernel 4: window reverse + residual + LN2 (x2 stored bf16) ---------
__global__ __launch_bounds__(256) void k_merge_ln2(
    const float* __restrict__ x, const u16* __restrict__ ao,
    const float* __restrict__ g, const float* __restrict__ b,
    u16* __restrict__ x2b, u16* __restrict__ xn2)
{
  int m = blockIdx.x * 4 + (threadIdx.x >> 6);
  int lane = threadIdx.x & 63;
  int bb = m / 25088, l = m - bb * 25088;
  int d = l / 3136; int rem = l - d * 3136; int h = rem / 56, w = rem - h * 56;
  int dsh = (d + 7) & 7;
  int hsh = h - 3; if (hsh < 0) hsh += 56;
  int wsh = w - 3; if (wsh < 0) wsh += 56;
  int wd = dsh >> 1, td = dsh & 1;
  int wh = hsh / 7, th = hsh - wh * 7;
  int ww = wsh / 7, tw = wsh - ww * 7;
  int win = (bb << 8) + (wd << 6) + (wh << 3) + ww;
  int tok = td * 49 + th * 7 + tw;
  const u16* ar = ao + ((size_t)win * 98 + tok) * 192;
  const float* xr = x + (size_t)m * 192;
  float v0 = xr[lane      ] + bf2f(ar[lane      ]);
  float v1 = xr[lane + 64 ] + bf2f(ar[lane + 64 ]);
  float v2 = xr[lane + 128] + bf2f(ar[lane + 128]);
  u16* x2r = x2b + (size_t)m * 192;
  x2r[lane] = f2bf(v0); x2r[lane + 64] = f2bf(v1); x2r[lane + 128] = f2bf(v2);
  float mu  = wsum(v0 + v1 + v2) * (1.f / 192.f);
  float sq  = wsum(v0 * v0 + v1 * v1 + v2 * v2) * (1.f / 192.f);
  float inv = rsqrtf(sq - mu * mu + 1e-5f);
  u16* nr = xn2 + (size_t)m * 192;
  nr[lane      ] = f2bf((v0 - mu) * inv * g[lane      ] + b[lane      ]);
  nr[lane + 64 ] = f2bf((v1 - mu) * inv * g[lane + 64 ] + b[lane + 64 ]);
  nr[lane + 128] = f2bf((v2 - mu) * inv * g[lane + 128] + b[lane + 128]);
}

// ---------------- streaming GEMM (K=192): wide-N blocks -------------------------------
// Block = 192 N-cols x (MG*64) M-rows; 4 waves, wave = 64 rows x 48 cols (acc[4][3]).
// W-slice hoisted ONCE into regs (wf[3][6] per wave); A via gload_lds dbuf.
// 72 MFMA per barrier (2x the old 96-col shape); A staged NB x (NB=NTOT/192).
// mg-MAJOR grid + XCD chunking: A-sharers contiguous -> same XCD L2.
// RELU instantiation carries 144 tail blocks that convert w2 fp32->bf16 (overlapped).
template<bool RELU, int NTOT>
__global__ __launch_bounds__(256) void k_gemm3(
    const u16* __restrict__ A, const u16* __restrict__ Wb, const float* __restrict__ bias,
    u16* __restrict__ C, const float* __restrict__ w2src, u16* __restrict__ w2dst)
{
  constexpr int MG = 4;
  constexpr int NB = NTOT / 192;
  constexpr int MGROUPS = 50176 / (MG * 64);   // 196
  constexpr int MAINW = NB * MGROUPS;
  __shared__ u16 As[2][64 * 192];   // 2 x 24576 B
  int bid = blockIdx.x;
  if (RELU && bid >= MAINW) {
    int i = (bid - MAINW) * 256 + threadIdx.x;
    if (i < 36864) {
      f32x4 v = reinterpret_cast<const f32x4*>(w2src)[i];
      u16x4 o; o[0] = f2bf(v[0]); o[1] = f2bf(v[1]); o[2] = f2bf(v[2]); o[3] = f2bf(v[3]);
      reinterpret_cast<u16x4*>(w2dst)[i] = o;
    }
    return;
  }
  bid = xcd_swz(bid, MAINW);
  int mg = bid / NB, nb = bid - mg * NB;   // mg-major: A-sharers adjacent
  int m_base = mg * (MG * 64);
  int tid = threadIdx.x, lane = tid & 63, wv = tid >> 6;
  int lr = lane & 15, lg = lane >> 4;
  int n0 = nb * 192 + wv * 48;             // wave owns a 48-col quarter

  auto stage = [&](int buf, int mt) {
    const char* gb = (const char*)(A + (size_t)(m_base + mt * 64) * 192);
    char* lb = (char*)As[buf] + wv * 6144;
#pragma unroll
    for (int c = 0; c < 6144; c += 1024) {
      int o = wv * 6144 + c + lane * 16;
      int row = (int)((u32)o / 384u);
      int slot = (o - row * 384) >> 4;
      int sw = (slot & ~7) | ((slot & 7) ^ (row & 7));
      gload16(gb + (size_t)row * 384 + sw * 16, lb + c);
    }
  };

  stage(0, 0);   // issue first A-tile ASAP; W-loads below overlap its latency

  s16x8 wf[3][6];
  const u16* wbase = Wb + (size_t)(n0 + lr) * 192 + lg * 8;
#pragma unroll
  for (int nf = 0; nf < 3; ++nf)
#pragma unroll
    for (int ks = 0; ks < 6; ++ks)
      wf[nf][ks] = *reinterpret_cast<const s16x8*>(wbase + (size_t)nf * 16 * 192 + ks * 32);
  float bs[3];
#pragma unroll
  for (int nf = 0; nf < 3; ++nf) bs[nf] = bias[n0 + nf * 16 + lr];

  __syncthreads();
  for (int i = 0; i < MG; ++i) {
    int cur = i & 1;
    if (i + 1 < MG) stage(cur ^ 1, i + 1);
    f32x4 acc[4][3];
#pragma unroll
    for (int mi = 0; mi < 4; ++mi)
#pragma unroll
      for (int nf = 0; nf < 3; ++nf) acc[mi][nf] = {0.f, 0.f, 0.f, 0.f};
#pragma unroll
    for (int ks = 0; ks < 6; ++ks) {
      int s = ks * 4 + lg;
#pragma unroll
      for (int mi = 0; mi < 4; ++mi) {
        s16x8 a0 = *frag(As[cur], mi * 16 + lr, s);
#pragma unroll
        for (int nf = 0; nf < 3; ++nf)
          acc[mi][nf] = __builtin_amdgcn_mfma_f32_16x16x32_bf16(a0, wf[nf][ks], acc[mi][nf], 0, 0, 0);
      }
    }
    int m0 = m_base + i * 64;
#pragma unroll
    for (int mi = 0; mi < 4; ++mi)
#pragma unroll
      for (int nf = 0; nf < 3; ++nf)
#pragma unroll
        for (int r = 0; r < 4; ++r) {
          int m = m0 + mi * 16 + lg * 4 + r;
          int n = n0 + nf * 16 + lr;
          float val = acc[mi][nf][r] + bs[nf];
          if (RELU) val = fmaxf(val, 0.f);
          C[(size_t)m * NTOT + n] = f2bf(val);
        }
    __syncthreads();
  }
}

// ---------------- MLP2 GEMM (K=768): 512 thr / 8 waves, LDS-staged A+W ----------
// mb-major: the 2 blocks sharing an A-slice are adjacent -> same XCD.
__global__ __launch_bounds__(512) void k_gemm2mlp2(
    const u16* __restrict__ A, const u16* __restrict__ Wb, const float* __restrict__ bias,
    const u16* __restrict__ x2b, float* __restrict__ of)
{
  constexpr int MB = 784;
  constexpr int KTOT = 768;
  __shared__ u16 As[64 * 192];     // 24576 B
  __shared__ u16 Ws[96 * 192];     // 36864 B
  int bid = xcd_swz(blockIdx.x, 2 * MB);
  int mb = bid >> 1, nb = bid & 1;
  int m0 = mb * 64, n0 = nb * 96;
  int tid = threadIdx.x, lane = tid & 63, wv = tid >> 6;
  int lr = lane & 15, lg = lane >> 4;
  int wm = wv >> 1, wn = wv & 1;

  f32x4 acc[3];
#pragma unroll
  for (int j = 0; j < 3; ++j) acc[j] = {0.f, 0.f, 0.f, 0.f};

  for (int kc = 0; kc < 4; ++kc) {
    if (kc) __syncthreads();
    if (wv < 4) {
      const char* gb = (const char*)(A + (size_t)m0 * KTOT + kc * 192);
      int base = wv * 6144;
#pragma unroll
      for (int c = 0; c < 6144; c += 1024) {
        int o = base + c + lane * 16;
        int row = (int)((u32)o / 384u);
        int slot = (o - row * 384) >> 4;
        int sw = (slot & ~7) | ((slot & 7) ^ (row & 7));
        gload16(gb + (size_t)row * (KTOT * 2) + sw * 16, (char*)As + base + c);
      }
    } else {
      const char* gb = (const char*)(Wb + (size_t)n0 * KTOT + kc * 192);
      int base = (wv - 4) * 9216;
#pragma unroll
      for (int c = 0; c < 9216; c += 1024) {
        int o = base + c + lane * 16;
        int row = (int)((u32)o / 384u);
        int slot = (o - row * 384) >> 4;
        int sw = (slot & ~7) | ((slot & 7) ^ (row & 7));
        gload16(gb + (size_t)row * (KTOT * 2) + sw * 16, (char*)Ws + base + c);
      }
    }
    __syncthreads();
#pragma unroll
    for (int ks = 0; ks < 6; ++ks) {
      int s = ks * 4 + lg;
      s16x8 a0 = *frag(As, wm * 16 + lr, s);
#pragma unroll
      for (int nf = 0; nf < 3; ++nf) {
        s16x8 bfr = *frag(Ws, wn * 48 + nf * 16 + lr, s);
        acc[nf] = __builtin_amdgcn_mfma_f32_16x16x32_bf16(a0, bfr, acc[nf], 0, 0, 0);
      }
    }
  }
#pragma unroll
  for (int nf = 0; nf < 3; ++nf)
#pragma unroll
    for (int r = 0; r < 4; ++r) {
      int m = m0 + wm * 16 + lg * 4 + r;
      int n = n0 + wn * 48 + nf * 16 + lr;
      size_t idx = (size_t)m * 192 + n;
      of[idx] = fmaxf(acc[nf][r] + bias[n], 0.f) + bf2f(x2b[idx]);
    }
}

// ---------------- kernel 3: windowed attention via MFMA -------------------
// 7 waves (448 thr), one 16-row stripe per wave. K fragments staged in LDS once per
// block; bias (incl. mask + col-pad -1e30) folded into MFMA C-operand; no max pass.
__global__ __launch_bounds__(448, 2) void k_attn_mfma(
    const u16* __restrict__ qkvc, const u16* __restrict__ biasT, u16* __restrict__ ao)
{
  __shared__ u16 P[7][16 * 128];   // 28672 B per-wave unnormalized probs, slot-swizzled
  __shared__ u16 Vt[32 * 136];     // 8704 B V transposed (d-major), cols 98..135 zero
  __shared__ u16 Ks[98 * 40];      // 7840 B K rows (pad 40 u16 = 80 B: 16B-aligned)

  int bid = xcd_swz(blockIdx.x, 3072);   // 6 heads of a window land on one XCD (L2 reuse)
  int win = bid / 6, head = bid - win * 6;
  int tid = threadIdx.x, lane = tid & 63, wv = tid >> 6;   // wv = stripe 0..6
  int lr = lane & 15, lg = lane >> 4;
  size_t rb = (size_t)(win * 98) * 576;
  const u16* qp0 = qkvc + rb + head * 32;          // q (pre-scaled)
  const u16* kp0 = qkvc + rb + 192 + head * 32;    // k
  const u16* vp0 = qkvc + rb + 384 + head * 32;    // v

  int wrem = win & 255;
  int wd = wrem >> 6, wh = (wrem >> 3) & 7, ww = wrem & 7;
  int cls = ((wd == 3) ? 4 : 0) | ((wh == 7) ? 2 : 0) | ((ww == 7) ? 1 : 0);
  const u16* bT = biasT + (size_t)(cls * 6 + head) * 112 * 112;

  // ---- wave-local global loads first (8 loads -> stay in flight) ----
  int qrow = wv * 16 + lr; if (qrow > 97) qrow = 97;
  s16x8 qf = *reinterpret_cast<const s16x8*>(qp0 + (size_t)qrow * 576 + lg * 8);
  u16x4 b4[7];
#pragma unroll
  for (int j = 0; j < 7; ++j) {
    int col = j * 16 + lr;                       // 0..111, table covers pad cols
    b4[j] = *reinterpret_cast<const u16x4*>(bT + (size_t)col * 112 + wv * 16 + lg * 4);
  }

  // ---- stage V transposed + K row-major (one pass); zero Vt pad cols ----
  for (int u = tid; u < 98 * 16; u += 448) {
    int tok = u >> 4, dp = (u & 15) * 2;
    u32 w = *reinterpret_cast<const u32*>(vp0 + (size_t)tok * 576 + dp);
    Vt[dp * 136 + tok]       = (u16)(w & 0xFFFFu);
    Vt[(dp + 1) * 136 + tok] = (u16)(w >> 16);
    u32 wk = *reinterpret_cast<const u32*>(kp0 + (size_t)tok * 576 + dp);
    *reinterpret_cast<u32*>(&Ks[tok * 40 + dp]) = wk;
  }
  for (int u = tid; u < 32 * 19; u += 448) {
    int d = u / 19, kslot = u - d * 19;
    *reinterpret_cast<u32*>(reinterpret_cast<char*>(Vt) + d * 272 + 196 + kslot * 4) = 0;
  }
  __syncthreads();

  // ---- QK^T: K fragment from LDS, bias (incl. mask & pad) as the C operand ----
  f32x4 s[7];
  __builtin_amdgcn_s_setprio(1);
#pragma unroll
  for (int j = 0; j < 7; ++j) {
    int row = j * 16 + lr; if (row > 97) row = 97;
    s16x8 kfj = *reinterpret_cast<const s16x8*>(&Ks[row * 40 + lg * 8]);
    f32x4 c4;
#pragma unroll
    for (int r = 0; r < 4; ++r) c4[r] = bf2f(b4[j][r]);
    s[j] = __builtin_amdgcn_mfma_f32_16x16x32_bf16(qf, kfj, c4, 0, 0, 0);
  }
  __builtin_amdgcn_s_setprio(0);

  // ---- softmax without max pass (scores in [-101, ~2]; exp exact in fp32) ----
  float sm[4] = {0.f, 0.f, 0.f, 0.f};
#pragma unroll
  for (int j = 0; j < 7; ++j)
#pragma unroll
    for (int r = 0; r < 4; ++r) {
      float p = __expf(s[j][r]);
      s[j][r] = p;
      sm[r] += p;
    }
#pragma unroll
  for (int m = 1; m < 16; m <<= 1)
#pragma unroll
    for (int r = 0; r < 4; ++r) sm[r] += __shfl_xor(sm[r], m, 64);
  float rinv[4];
#pragma unroll
  for (int r = 0; r < 4; ++r) rinv[r] = 1.f / sm[r];

  // ---- write unnormalized P to this wave's LDS stripe (16B-slot XOR row&7) ----
#pragma unroll
  for (int j = 0; j < 7; ++j) {
    int col = j * 16 + lr;
    int slot = col >> 3, wi = col & 7;
#pragma unroll
    for (int r = 0; r < 4; ++r) {
      int lrow = lg * 4 + r;
      P[wv][lrow * 128 + (((slot ^ (lrow & 7)) << 3) | wi)] = f2bf(s[j][r]);
    }
  }
  if (lane < 32) {
    int lrow = lr;
    int slot = 14 + lg;
    u32x4 z4 = {0u, 0u, 0u, 0u};
    *reinterpret_cast<u32x4*>(&P[wv][lrow * 128 + ((slot ^ (lrow & 7)) << 3)]) = z4;
  }

  // ---- PV (wave-local; no barrier needed) ----
  f32x4 o0 = {0.f, 0.f, 0.f, 0.f}, o1 = {0.f, 0.f, 0.f, 0.f};
  __builtin_amdgcn_s_setprio(1);
#pragma unroll
  for (int kc = 0; kc < 4; ++kc) {
    int slot = kc * 4 + lg;
    s16x8 pf = *reinterpret_cast<const s16x8*>(&P[wv][lr * 128 + ((slot ^ (lr & 7)) << 3)]);
    s16x8 vf0 = *reinterpret_cast<const s16x8*>(&Vt[lr * 136 + kc * 32 + lg * 8]);
    s16x8 vf1 = *reinterpret_cast<const s16x8*>(&Vt[(16 + lr) * 136 + kc * 32 + lg * 8]);
    o0 = __builtin_amdgcn_mfma_f32_16x16x32_bf16(pf, vf0, o0, 0, 0, 0);
    o1 = __builtin_amdgcn_mfma_f32_16x16x32_bf16(pf, vf1, o1, 0, 0, 0);
  }
  __builtin_amdgcn_s_setprio(0);
#pragma unroll
  for (int r = 0; r < 4; ++r) {
    int t = wv * 16 + lg * 4 + r;
    if (t < 98) {
      size_t ob = ((size_t)win * 98 + t) * 192 + head * 32;
      ao[ob + lr]      = f2bf(o0[r] * rinv[r]);
      ao[ob + 16 + lr] = f2bf(o1[r] * rinv[r]);
    }
  }
}

extern "C" void kernel_launch(void* const* d_in, const int* in_sizes, int n_in,
                              void* d_out, int out_size, void* d_ws, size_t ws_size,
                              hipStream_t stream) {
  (void)in_sizes; (void)n_in; (void)out_size; (void)ws_size;
  const float* x    = (const float*)d_in[0];
  const float* n1g  = (const float*)d_in[1];
  const float* n1b  = (const float*)d_in[2];
  const float* qkvw = (const float*)d_in[3];
  const float* qkvb = (const float*)d_in[4];
  const float* relt = (const float*)d_in[5];
  const float* n2g  = (const float*)d_in[6];
  const float* n2b  = (const float*)d_in[7];
  const float* w1   = (const float*)d_in[8];
  const float* b1   = (const float*)d_in[9];
  const float* w2   = (const float*)d_in[10];
  const float* b2   = (const float*)d_in[11];
  float* out = (float*)d_out;
  char* ws = (char*)d_ws;

  constexpr size_t SZB = 50176ull * 192 * 2;  // one bf16 activation plane
  u16*  xw    = (u16*)(ws);               // plane0: xw -> ao -> w2b (sequential lives)
  u16*  qkvc  = (u16*)(ws + SZB);         // 50176 x 576 bf16 (3 planes)
  u16*  x2b   = (u16*)(ws + SZB);         // overlaps qkvc head (dead after attention)
  u16*  xn2   = (u16*)(ws + 3 * SZB);     // overlaps qkvc tail
  u16*  h1    = (u16*)(ws + 4 * SZB);
  u16*  ao    = xw;
  u16*  w2b   = xw;                       // plane0 after merge_ln2 consumed ao

  // d_out head (dead until final GEMM writes it): bf16 weights, permuted bias, biasT.
  u16*   qkvwb = (u16*)out;                            // 221,184 B
  u16*   w1b   = (u16*)((char*)out + 221184);          // 294,912 B
  float* pbias = (float*)((char*)out + 516096);        // 2,304 B
  u16*   biasT = (u16*)((char*)out + 520192);          // 1,204,224 B

  // 1) prep (weights + bias table) fused with LN1 (independent work, overlapped)
  k_prep<<<2604 + 12544, 256, 0, stream>>>(qkvw, qkvb, qkvwb, pbias, w1, w1b, relt, biasT,
                                           x, n1g, n1b, xw);
  // 2) QKV GEMM (wide-N: 3 x 196 blocks)
  k_gemm3<false, 576><<<3 * 196, 256, 0, stream>>>(xw, qkvwb, pbias, qkvc, nullptr, nullptr);
  // 3) attention
  k_attn_mfma<<<3072, 448, 0, stream>>>(qkvc, biasT, ao);
  // 4) merge + LN2
  k_merge_ln2<<<12544, 256, 0, stream>>>(x, ao, n2g, n2b, x2b, xn2);
  // 5) MLP1 (wide-N: 4 x 196 main + 144 w2-conv tail blocks, overlapped)
  k_gemm3<true, 768><<<4 * 196 + 144, 256, 0, stream>>>(xn2, w1b, b1, h1, w2, w2b);
  // 6) MLP2 + residual
  k_gemm2mlp2<<<784 * 2, 512, 0, stream>>>(h1, w2b, b2, x2b, out);
}